// Round 8
// baseline (52927.081 us; speedup 1.0000x reference)
//
#include <hip/hip_runtime.h>
#include <hip/hip_bf16.h>
#include <stdint.h>

// RVAE forward: 3 sequential GRU scans (L=512, B=256, H=256) on 256 WGs x 512 thr.
// Group g (wgid&31) owns batch rows [8g,8g+8); slice s (wgid>>5) owns units [32s,32s+32).
// R7: VGPR-resident weights (thread=(u,kap)) + DPP reduce + pointwise-in-kap15
// + flag publish/poll exchange + posterior-from-staged-h + coalesced staged stores.

struct RvaeParams {
  const float *x, *eps;
  const float *fx_W, *fx_b;
  const float *fz_W1, *fz_b1, *fz_W2, *fz_b2;
  const float *p1_Wih, *p1_Whh, *p1_bih, *p1_bhh;
  const float *p2_Wih, *p2_Whh, *p2_bih, *p2_bhh;
  const float *pn_locW, *pn_locb, *pn_scaleW, *pn_scaleb;
  const float *th_Wih, *th_Whh, *th_bih, *th_bhh;
  const float *tn_locW, *tn_locb;
  float* out;
  unsigned* flags;   // [32 groups][8 slices] monotone step tags
  float* hbuf;       // [2][256][256] parity-double-buffered hidden state
  float* zf_seq;     // [512][256][32]
  unsigned* xh;      // [512 t][256 row][128] packed 2x bf16 units
};

__device__ __forceinline__ float agent_load_f32(const float* p) {
  return __hip_atomic_load(p, __ATOMIC_RELAXED, __HIP_MEMORY_SCOPE_AGENT);
}
__device__ __forceinline__ unsigned agent_load_u32_acq(const unsigned* p) {
  return __hip_atomic_load(p, __ATOMIC_ACQUIRE, __HIP_MEMORY_SCOPE_AGENT);
}
__device__ __forceinline__ unsigned agent_load_u32(const unsigned* p) {
  return __hip_atomic_load(p, __ATOMIC_RELAXED, __HIP_MEMORY_SCOPE_AGENT);
}
__device__ __forceinline__ unsigned long long agent_load_u64(const unsigned long long* p) {
  return __hip_atomic_load(p, __ATOMIC_RELAXED, __HIP_MEMORY_SCOPE_AGENT);
}
__device__ __forceinline__ void agent_store_f32(float* p, float v) {
  __hip_atomic_store(p, v, __ATOMIC_RELAXED, __HIP_MEMORY_SCOPE_AGENT);
}
__device__ __forceinline__ void agent_store_u32(unsigned* p, unsigned v) {
  __hip_atomic_store(p, v, __ATOMIC_RELAXED, __HIP_MEMORY_SCOPE_AGENT);
}
__device__ __forceinline__ void agent_store_u32_rel(unsigned* p, unsigned v) {
  __hip_atomic_store(p, v, __ATOMIC_RELEASE, __HIP_MEMORY_SCOPE_AGENT);
}
__device__ __forceinline__ float sigm(float v) { return 1.0f / (1.0f + __expf(-v)); }
__device__ __forceinline__ float ftanh(float v) { return 1.0f - 2.0f / (__expf(2.0f * v) + 1.0f); }
__device__ __forceinline__ float softplusf(float v) { return (v > 15.0f) ? v : log1pf(__expf(v)); }
__device__ __forceinline__ unsigned f2bf(float x) {  // round-to-nearest-even bf16
  unsigned uu = __float_as_uint(x);
  return (uu + 0x7fffu + ((uu >> 16) & 1u)) >> 16;
}
template<int CTRL>
__device__ __forceinline__ float dpp_add(float v) {  // v += dpp_shifted(v)
  int xi = __builtin_amdgcn_update_dpp(0, __float_as_int(v), CTRL, 0xF, 0xF, true);
  return v + __int_as_float(xi);
}
__device__ __forceinline__ float row_reduce16(float v) {
  v = dpp_add<0x111>(v); v = dpp_add<0x112>(v); v = dpp_add<0x114>(v); v = dpp_add<0x118>(v);
  return v;  // lane (row*16+15) holds the 16-lane sum
}

extern "C" __global__ void __launch_bounds__(512, 2) rvae_main(RvaeParams P) {
  // hL swizzle: h[b][k] at b*320 + (k>>4)*20 + (k&15) -> kap-chunk reads are <=2-way.
  __shared__ __align__(16) float hL[2560];
  __shared__ __align__(16) float inL[544];    // stride 68 (phase1) / 36 (phase2/3)
  __shared__ __align__(16) float hnewL[288];  // [8][36]
  __shared__ __align__(16) unsigned xh16u[144]; // [8][18] u32 = u16[8][36]
  __shared__ __align__(16) float SBp[4160];   // [8][520] posterior weights (phase2)
  __shared__ __align__(16) float xhL[2112];   // [8][264] staged xh_t as f32 (phase2)
  __shared__ float pL[72];                    // [8][9]
  __shared__ float hmL2[16];
  __shared__ float bihL[96], bhhL[96];
  __shared__ float fxwL[64], fxbL[64];
  __shared__ float fzW1L[8], fzb1L[2], fzW2L[64], fzb2L[32];
  __shared__ float pnlb[4], pnsb[4], tnwL[32];

  const int tid = threadIdx.x;
  const int wgid = blockIdx.x;
  const int s = wgid >> 5, g = wgid & 31;   // 8 slices of a group differ by 32 -> same XCD
  const int u = tid >> 4, kap = tid & 15;
  const int lane = tid & 63;
  const int hoff = ((s * 32 + u) >> 4) * 20 + ((s * 32 + u) & 15);
  unsigned* gflags = P.flags + g * 8;

  if (tid < 64) { fxwL[tid] = P.fx_W[tid]; fxbL[tid] = P.fx_b[tid]; fzW2L[tid] = P.fz_W2[tid]; }
  if (tid < 8)  fzW1L[tid] = P.fz_W1[tid];
  if (tid < 2)  fzb1L[tid] = P.fz_b1[tid];
  if (tid < 32) { fzb2L[tid] = P.fz_b2[tid]; tnwL[tid] = P.tn_locW[s * 32 + tid]; }
  if (tid < 4)  { pnlb[tid] = P.pn_locb[tid]; pnsb[tid] = P.pn_scaleb[tid]; }

  float whr[16], whz[16], whn[16];  // Whh[gate][s*32+u][kap*16..+16]
  float wir[4], wiz[4], win[4];
  float pr[8], pz[8], pni[8], pnh[8];
  unsigned long long q0, q1;

  auto poll = [&](unsigned tag) {
    int guard = 0;
    for (;;) {
      unsigned f = agent_load_u32_acq(gflags + (lane & 7));
      if (__all((int)(f >= tag))) break;
      __builtin_amdgcn_s_sleep(1);
      if (++guard > (1 << 22)) break;  // fail loud, never hang
    }
  };
  auto load_whh_regs = [&](const float* Whh) {
    const float* base = Whh + (size_t)(s * 32 + u) * 256 + kap * 16;
#pragma unroll
    for (int c = 0; c < 4; ++c) {
      float4 vr = *(const float4*)(base + c * 4);
      float4 vz = *(const float4*)(base + 65536 + c * 4);
      float4 vn = *(const float4*)(base + 131072 + c * 4);
      whr[4*c+0]=vr.x; whr[4*c+1]=vr.y; whr[4*c+2]=vr.z; whr[4*c+3]=vr.w;
      whz[4*c+0]=vz.x; whz[4*c+1]=vz.y; whz[4*c+2]=vz.z; whz[4*c+3]=vz.w;
      whn[4*c+0]=vn.x; whn[4*c+1]=vn.y; whn[4*c+2]=vn.z; whn[4*c+3]=vn.w;
    }
  };
  auto load_wih64_regs = [&](const float* Wih) {
    const float* base = Wih + (size_t)(s * 32 + u) * 64 + kap * 4;
    float4 vr = *(const float4*)(base);
    float4 vz = *(const float4*)(base + 16384);
    float4 vn = *(const float4*)(base + 32768);
    wir[0]=vr.x; wir[1]=vr.y; wir[2]=vr.z; wir[3]=vr.w;
    wiz[0]=vz.x; wiz[1]=vz.y; wiz[2]=vz.z; wiz[3]=vz.w;
    win[0]=vn.x; win[1]=vn.y; win[2]=vn.z; win[3]=vn.w;
  };
  auto load_wih32_regs = [&](const float* Wih) {
    const float* base = Wih + (size_t)(s * 32 + u) * 32 + kap * 2;
    float2 vr = *(const float2*)(base);
    float2 vz = *(const float2*)(base + 8192);
    float2 vn = *(const float2*)(base + 16384);
    wir[0]=vr.x; wir[1]=vr.y; wiz[0]=vz.x; wiz[1]=vz.y; win[0]=vn.x; win[1]=vn.y;
  };
  auto load_bias = [&](const float* bih, const float* bhh) {
    if (tid < 96) {
      int gate = tid >> 5, u2 = tid & 31;
      bihL[tid] = bih[gate * 256 + s * 32 + u2];
      bhhL[tid] = bhh[gate * 256 + s * 32 + u2];
    }
  };
  auto h_issue = [&](int par) {
    const unsigned long long* hb =
        (const unsigned long long*)(P.hbuf + par * 65536 + g * 2048) + tid * 2;
    q0 = agent_load_u64(hb); q1 = agent_load_u64(hb + 1);
  };
  auto stage_h = [&](bool zero) {
    int bb = tid >> 6, k4 = tid & 63;
    float4 v;
    if (zero) v = make_float4(0.f, 0.f, 0.f, 0.f);
    else { union { unsigned long long q[2]; float f[4]; } cv; cv.q[0]=q0; cv.q[1]=q1; v = *(float4*)cv.f; }
    *(float4*)(hL + bb * 320 + (k4 >> 2) * 20 + (k4 & 3) * 4) = v;
  };
  auto gi64 = [&]() {
#pragma unroll
    for (int b = 0; b < 8; ++b) {
      float4 iv = *(const float4*)(inL + b * 68 + kap * 4);
      pr[b]  = fmaf(wir[0], iv.x, fmaf(wir[1], iv.y, fmaf(wir[2], iv.z, wir[3] * iv.w)));
      pz[b]  = fmaf(wiz[0], iv.x, fmaf(wiz[1], iv.y, fmaf(wiz[2], iv.z, wiz[3] * iv.w)));
      pni[b] = fmaf(win[0], iv.x, fmaf(win[1], iv.y, fmaf(win[2], iv.z, win[3] * iv.w)));
      pnh[b] = 0.0f;
    }
  };
  auto gi32 = [&]() {
#pragma unroll
    for (int b = 0; b < 8; ++b) {
      float2 iv = *(const float2*)(inL + b * 36 + kap * 2);
      pr[b]  = fmaf(wir[0], iv.x, wir[1] * iv.y);
      pz[b]  = fmaf(wiz[0], iv.x, wiz[1] * iv.y);
      pni[b] = fmaf(win[0], iv.x, win[1] * iv.y);
      pnh[b] = 0.0f;
    }
  };
  auto gh_accum = [&]() {
#pragma unroll
    for (int b = 0; b < 8; ++b) {
      const float* hp = hL + b * 320 + kap * 20;
      float4 hcv[4];
      hcv[0] = *(const float4*)(hp);     hcv[1] = *(const float4*)(hp + 4);
      hcv[2] = *(const float4*)(hp + 8); hcv[3] = *(const float4*)(hp + 12);
      float r = pr[b], z = pz[b], n = pnh[b];
#pragma unroll
      for (int c = 0; c < 4; ++c) {
        r = fmaf(whr[4*c+0], hcv[c].x, r); r = fmaf(whr[4*c+1], hcv[c].y, r);
        r = fmaf(whr[4*c+2], hcv[c].z, r); r = fmaf(whr[4*c+3], hcv[c].w, r);
        z = fmaf(whz[4*c+0], hcv[c].x, z); z = fmaf(whz[4*c+1], hcv[c].y, z);
        z = fmaf(whz[4*c+2], hcv[c].z, z); z = fmaf(whz[4*c+3], hcv[c].w, z);
        n = fmaf(whn[4*c+0], hcv[c].x, n); n = fmaf(whn[4*c+1], hcv[c].y, n);
        n = fmaf(whn[4*c+2], hcv[c].z, n); n = fmaf(whn[4*c+3], hcv[c].w, n);
      }
      pr[b] = r; pz[b] = z; pnh[b] = n;
    }
  };
  auto reduce4 = [&]() {
#pragma unroll
    for (int b = 0; b < 8; ++b) {
      pr[b] = row_reduce16(pr[b]);  pz[b] = row_reduce16(pz[b]);
      pni[b] = row_reduce16(pni[b]); pnh[b] = row_reduce16(pnh[b]);
    }
  };
  // kap==15 lanes: gate math for all 8 rows of own unit; stage results in LDS.
  auto pointwise = [&](bool storeXh) {
    if (kap == 15) {
#pragma unroll
      for (int b = 0; b < 8; ++b) {
        float rr = sigm(pr[b] + bihL[u] + bhhL[u]);
        float zz = sigm(pz[b] + bihL[32 + u] + bhhL[32 + u]);
        float nn = ftanh(fmaf(rr, pnh[b] + bhhL[64 + u], pni[b] + bihL[64 + u]));
        float hold = hL[b * 320 + hoff];
        float hnew = fmaf(zz, hold - nn, nn);
        hnewL[b * 36 + u] = hnew;
        if (storeXh) ((unsigned short*)xh16u)[b * 36 + u] = (unsigned short)f2bf(hnew);
      }
    }
  };
  auto store_h = [&](int outPar) {   // tid<256: two contiguous 128B runs per wave
    if (tid < 256) {
      int b = tid >> 5, c = tid & 31;
      agent_store_f32(P.hbuf + outPar * 65536 + (g * 8 + b) * 256 + s * 32 + c,
                      hnewL[b * 36 + c]);
    }
  };
  auto fence_flag = [&](unsigned tag) {
    asm volatile("s_waitcnt vmcnt(0)" ::: "memory");
    __syncthreads();
    if (tid == 0) agent_store_u32_rel(gflags + s, tag);
  };

  //================= Phase 1: backward GRU (phi1), xh packed bf16 =================
  load_whh_regs(P.p1_Whh);
  load_wih64_regs(P.p1_Wih);
  load_bias(P.p1_bih, P.p1_bhh);
  __syncthreads();
  { int bb = tid >> 6, k = tid & 63;
    float xv = P.x[(size_t)(g * 8 + bb) * 512 + 511];
    inL[bb * 68 + k] = ftanh(fmaf(xv, fxwL[k], fxbL[k])); }
  __syncthreads();
#pragma unroll 1
  for (int t = 0; t < 512; ++t) {
    if (t) { poll(t); h_issue(t & 1); }
    gi64();                         // LDS reads overlap global h latency
    stage_h(t == 0);
    __syncthreads();                // S: hL staged
    gh_accum();
    reduce4();
    pointwise(true);
    int t_in = 511 - t;
    if (t < 511) {                  // featurize next col (all waves past their gi64)
      int bb = tid >> 6, k = tid & 63;
      float xv = P.x[(size_t)(g * 8 + bb) * 512 + (t_in - 1)];
      inL[bb * 68 + k] = ftanh(fmaf(xv, fxwL[k], fxbL[k]));
    }
    __syncthreads();                // A: hnewL/xh16u/inL visible
    store_h((t + 1) & 1);
    if (tid < 128) {                // xh store: 4 rows x 64B per wave
      int b = tid >> 4, c = tid & 15;
      agent_store_u32(P.xh + (size_t)t_in * 32768 + (g * 8 + b) * 128 + s * 16 + c,
                      xh16u[b * 18 + c]);
    }
    fence_flag(t + 1);
  }

  //================= Phase 2: encoder GRU (phi2) + posterior + feat_z =================
  load_whh_regs(P.p2_Whh);
  load_wih32_regs(P.p2_Wih);
  load_bias(P.p2_bih, P.p2_bhh);
  for (int i = tid; i < 2048; i += 512) {
    int o = i >> 9, c = i & 511;
    SBp[o * 520 + c] = P.pn_locW[i];
    SBp[(4 + o) * 520 + c] = P.pn_scaleW[i];
  }
  for (int i = tid; i < 288; i += 512) inL[i] = 0.0f;  // zf0 = 0
  poll(512);                         // all slices done with phase-1 reads
  __syncthreads();
  auto stage_xhL = [&](unsigned xa, unsigned xb) {
    int i0 = tid, i1 = tid + 512;
    *(float2*)(xhL + (i0 >> 7) * 264 + (i0 & 127) * 2) =
        make_float2(__uint_as_float((xa & 0xffffu) << 16), __uint_as_float(xa & 0xffff0000u));
    *(float2*)(xhL + (i1 >> 7) * 264 + (i1 & 127) * 2) =
        make_float2(__uint_as_float((xb & 0xffffu) << 16), __uint_as_float(xb & 0xffff0000u));
  };
  auto pblock = [&](int tp, bool toIn) {   // z_tp = posterior(staged zh, xh_tp); zf
    {
      int b = tid >> 6, o = (tid >> 3) & 7, c = tid & 7;
      const float* wrow = SBp + o * 520 + c * 64;
      float acc = 0.f;
#pragma unroll
      for (int m = 0; m < 16; ++m) {
        int r = (m + 2 * c) & 15;          // rotation de-banks SBp reads
        float4 w = *(const float4*)(wrow + r * 4);
        float4 v;
        if (c < 4) { int k = c * 64 + r * 4;
          v = *(const float4*)(hL + b * 320 + (k >> 4) * 20 + (k & 15)); }
        else v = *(const float4*)(xhL + b * 264 + (c - 4) * 64 + r * 4);
        acc = fmaf(v.x, w.x, fmaf(v.y, w.y, fmaf(v.z, w.z, fmaf(v.w, w.w, acc))));
      }
      acc = dpp_add<0x111>(acc); acc = dpp_add<0x112>(acc); acc = dpp_add<0x114>(acc);
      if (c == 7) pL[b * 9 + o] = acc;
    }
    __syncthreads();
    if (tid < 16) {
      int bb = tid >> 1, m = tid & 1;
      float a = fzb1L[m];
#pragma unroll
      for (int zi = 0; zi < 4; ++zi) {
        float loc = pL[bb * 9 + zi] + pnlb[zi];
        float sc = softplusf(pL[bb * 9 + 4 + zi] + pnsb[zi]);
        float e = P.eps[((size_t)tp * 256 + g * 8 + bb) * 4 + zi];
        a = fmaf(fmaf(sc, e, loc), fzW1L[m * 4 + zi], a);
      }
      hmL2[bb * 2 + m] = ftanh(a);
    }
    __syncthreads();
    if (tid < 256) {
      int bb = tid >> 5, o = tid & 31;
      float zf = ftanh(fmaf(hmL2[bb * 2], fzW2L[o * 2],
                       fmaf(hmL2[bb * 2 + 1], fzW2L[o * 2 + 1], fzb2L[o])));
      if (toIn) inL[bb * 36 + o] = zf;
      if (s == 0) agent_store_f32(P.zf_seq + ((size_t)tp * 256 + g * 8 + bb) * 32 + o, zf);
    }
    __syncthreads();
  };
#pragma unroll 1
  for (int t = 0; t < 512; ++t) {
    unsigned xa = 0, xb = 0;
    if (t) {
      poll(1024 + t);
      h_issue(t & 1);
      const unsigned* xp = P.xh + (size_t)(t - 1) * 32768 + g * 1024;
      xa = agent_load_u32(xp + tid); xb = agent_load_u32(xp + tid + 512);
    }
    stage_h(t == 0);
    if (t) stage_xhL(xa, xb);
    __syncthreads();                 // S
    if (t) pblock(t - 1, true);      // zf_t -> inL; zf_seq[t-1]
    gi32();
    gh_accum();
    reduce4();
    pointwise(false);
    __syncthreads();                 // A
    store_h((t + 1) & 1);
    fence_flag(1024 + t + 1);
  }
  { // epilogue: z_511 from zh_512 (parity 0) + xh_511
    poll(1536);
    h_issue(0);
    const unsigned* xp = P.xh + (size_t)511 * 32768 + g * 1024;
    unsigned xa = agent_load_u32(xp + tid), xb = agent_load_u32(xp + tid + 512);
    stage_h(false);
    stage_xhL(xa, xb);
    __syncthreads();
    pblock(511, false);
  }

  //================= Phase 3: decoder GRU (th) + output projection =================
  load_whh_regs(P.th_Whh);
  load_wih32_regs(P.th_Wih);
  load_bias(P.th_bih, P.th_bhh);
  const float tnb = P.tn_locb[0];
  __syncthreads();
#pragma unroll 1
  for (int t = 0; t < 512; ++t) {
    float zfv = 0.f;
    if (tid < 256)
      zfv = agent_load_f32(P.zf_seq + ((size_t)t * 256 + g * 8 + (tid >> 5)) * 32 + (tid & 31));
    if (t) { poll(2048 + t); h_issue(t & 1); }
    if (tid < 256) inL[(tid >> 5) * 36 + (tid & 31)] = zfv;
    stage_h(t == 0);
    __syncthreads();                 // S
    gi32();
    gh_accum();
    reduce4();
    pointwise(false);
    __syncthreads();                 // A
    store_h((t + 1) & 1);
    fence_flag(2048 + t + 1);
    if (tid < 8) {                   // own-slice partial of out dot
      float acc = (s == 0) ? tnb : 0.f;
#pragma unroll 8
      for (int i = 0; i < 32; ++i) acc = fmaf(hnewL[tid * 36 + i], tnwL[i], acc);
      atomicAdd(P.out + (size_t)(g * 8 + tid) * 512 + t, acc);
    }
  }
}

extern "C" void kernel_launch(void* const* d_in, const int* in_sizes, int n_in,
                              void* d_out, int out_size, void* d_ws, size_t ws_size,
                              hipStream_t stream) {
  (void)in_sizes; (void)n_in; (void)ws_size;
  RvaeParams P;
  P.x        = (const float*)d_in[0];
  P.eps      = (const float*)d_in[1];
  P.fx_W     = (const float*)d_in[2];  P.fx_b     = (const float*)d_in[3];
  P.fz_W1    = (const float*)d_in[4];  P.fz_b1    = (const float*)d_in[5];
  P.fz_W2    = (const float*)d_in[6];  P.fz_b2    = (const float*)d_in[7];
  P.p1_Wih   = (const float*)d_in[8];  P.p1_Whh   = (const float*)d_in[9];
  P.p1_bih   = (const float*)d_in[10]; P.p1_bhh   = (const float*)d_in[11];
  P.p2_Wih   = (const float*)d_in[12]; P.p2_Whh   = (const float*)d_in[13];
  P.p2_bih   = (const float*)d_in[14]; P.p2_bhh   = (const float*)d_in[15];
  P.pn_locW  = (const float*)d_in[16]; P.pn_locb  = (const float*)d_in[17];
  P.pn_scaleW= (const float*)d_in[18]; P.pn_scaleb= (const float*)d_in[19];
  P.th_Wih   = (const float*)d_in[20]; P.th_Whh   = (const float*)d_in[21];
  P.th_bih   = (const float*)d_in[22]; P.th_bhh   = (const float*)d_in[23];
  P.tn_locW  = (const float*)d_in[24]; P.tn_locb  = (const float*)d_in[25];
  P.out = (float*)d_out;
  char* ws = (char*)d_ws;
  P.flags  = (unsigned*)ws;                                 // 1 KB used (zeroed)
  P.hbuf   = (float*)(ws + 4096);                           // 524288 B
  P.zf_seq = (float*)(ws + 4096 + 524288);                  // 16777216 B
  P.xh     = (unsigned*)(ws + 4096 + 524288 + 16777216);    // 67108864 B

  hipMemsetAsync(d_out, 0, (size_t)out_size * sizeof(float), stream);
  hipMemsetAsync(d_ws, 0, 4096, stream);
  // 96KB dynamic LDS: pins occupancy to 1 WG/CU (static ~42KB + 96KB > 80KB).
  void* args[] = { (void*)&P };
  hipError_t err = hipLaunchCooperativeKernel((void*)rvae_main, dim3(256), dim3(512),
                                              args, 98304, stream);
  if (err != hipSuccess) {
    hipLaunchKernelGGL(rvae_main, dim3(256), dim3(512), 98304, stream, P);
  }
}